// Round 7
// baseline (220.856 us; speedup 1.0000x reference)
//
#include <hip/hip_runtime.h>
#include <hip/hip_bf16.h>

typedef __bf16 bf16;
typedef __bf16 bf16x8 __attribute__((ext_vector_type(8)));
typedef float f32x4 __attribute__((ext_vector_type(4)));

#define S_TOK 4096   // S*B
#define D_DIM 1024
#define NBLK 8
#define BDIM 128
#define E_DIM 768
#define NH 12
#define HD 64
#define QKVW 2304    // 3*E

// ---------------- K0: weight prep (transpose + bf16 cast) ----------------
__global__ __launch_bounds__(256) void prep_weights(
    const float* __restrict__ wq, const float* __restrict__ wk,
    const float* __restrict__ wv, const float* __restrict__ wfin,
    bf16* __restrict__ wcatT, bf16* __restrict__ wfinT) {
  long idx = (long)blockIdx.x * 256 + threadIdx.x;
  const long NCAT = (long)NBLK * QKVW * BDIM;  // 2359296
  if (idx < NCAT) {
    int k = idx & (BDIM - 1);
    long rem = idx >> 7;           // n*QKVW + j
    int j = (int)(rem % QKVW);
    int n = (int)(rem / QKVW);
    const float* src; int jj;
    if (j < 768) { src = wq; jj = j; }
    else if (j < 1536) { src = wk; jj = j - 768; }
    else { src = wv; jj = j - 1536; }
    float v = src[((long)n * BDIM + k) * E_DIM + jj];
    wcatT[idx] = (bf16)v;
  } else {
    long i2 = idx - NCAT;          // over 8*128*768 = 786432
    if (i2 < (long)NBLK * BDIM * E_DIM) {
      int e = (int)(i2 % E_DIM);
      long rem = i2 / E_DIM;
      int d = (int)(rem & (BDIM - 1));
      int n = (int)(rem >> 7);
      float v = wfin[((long)n * E_DIM + e) * BDIM + d];
      wfinT[i2] = (bf16)v;
    }
  }
}

// ---------------- K1: competition gating ----------------
__global__ __launch_bounds__(256) void gate_kernel(
    const float* __restrict__ x, const float* __restrict__ wcomp,
    bf16* __restrict__ xg) {
  int tok = blockIdx.x;
  int t = threadIdx.x;
  int n = t >> 5;          // block 0..7 (32 lanes each)
  int l = t & 31;
  const float* xrow = x + (long)tok * D_DIM + n * BDIM;
  float xv[4]; float part = 0.f;
#pragma unroll
  for (int i = 0; i < 4; ++i) {
    int d = l + i * 32;
    xv[i] = xrow[d];
    part += xv[i] * wcomp[n * BDIM + d];
  }
#pragma unroll
  for (int m = 16; m >= 1; m >>= 1) part += __shfl_xor(part, m, 64);
  __shared__ float logits[NBLK];
  __shared__ float comp[NBLK];
  if (l == 0) logits[n] = part;
  __syncthreads();
  if (t == 0) {
    float mx = logits[0];
#pragma unroll
    for (int i = 1; i < 8; ++i) mx = fmaxf(mx, logits[i]);
    float s = 0.f, e[8];
#pragma unroll
    for (int i = 0; i < 8; ++i) { e[i] = __expf(logits[i] - mx); s += e[i]; }
    float inv = 1.f / s;
#pragma unroll
    for (int i = 0; i < 8; ++i) comp[i] = e[i] * inv;
  }
  __syncthreads();
  float c = comp[n];
  bf16* dst = xg + ((long)n * S_TOK + tok) * BDIM;
#pragma unroll
  for (int i = 0; i < 4; ++i) dst[l + i * 32] = (bf16)(xv[i] * c);
}

// ---------------- shared GEMM machinery (m97 structure) ----------------
__device__ __forceinline__ void stage_tile(char* lds, const char* g, long rstride) {
  int wave = threadIdx.x >> 6, lane = threadIdx.x & 63;
#pragma unroll
  for (int s = 0; s < 8; ++s) {
    int instr = wave * 8 + s;               // 0..31, 1KB each
    int row = instr * 4 + (lane >> 4);      // 0..127
    int chunk = (lane & 15) ^ (row & 7);    // pre-swizzled source chunk
    const char* src = g + (long)row * rstride + chunk * 16;
    __builtin_amdgcn_global_load_lds(
        (const __attribute__((address_space(1))) void*)src,
        (__attribute__((address_space(3))) void*)(lds + instr * 1024), 16, 0, 0);
  }
}

__device__ __forceinline__ bf16x8 ld_frag(const char* lds, int row, int kchunk) {
  int chunk = kchunk ^ (row & 7);
  return *(const bf16x8*)(lds + row * 256 + chunk * 16);
}

__device__ __forceinline__ void mfma_slab(const char* ldsA, const char* ldsB,
                                          f32x4 acc[4][4], int wm, int wn, int lane) {
#pragma unroll
  for (int ks = 0; ks < 4; ++ks) {
    int kchunk = ks * 4 + (lane >> 4);
    bf16x8 af[4], bfr[4];
#pragma unroll
    for (int i = 0; i < 4; ++i) af[i] = ld_frag(ldsA, wm + i * 16 + (lane & 15), kchunk);
#pragma unroll
    for (int j = 0; j < 4; ++j) bfr[j] = ld_frag(ldsB, wn + j * 16 + (lane & 15), kchunk);
#pragma unroll
    for (int i = 0; i < 4; ++i)
#pragma unroll
      for (int j = 0; j < 4; ++j)
        acc[i][j] = __builtin_amdgcn_mfma_f32_16x16x32_bf16(af[i], bfr[j], acc[i][j], 0, 0, 0);
  }
}

// ---------------- K2: QKV block GEMM ----------------
__global__ __launch_bounds__(256) void qkv_gemm(
    const bf16* __restrict__ xg, const bf16* __restrict__ wcatT,
    bf16* __restrict__ qkv, int t0) {
  __shared__ char ldsA[32768];
  __shared__ char ldsB[32768];
  int nt = blockIdx.x;    // 0..17
  int mt = blockIdx.y;
  int blk = blockIdx.z;
  const char* Ab = (const char*)(xg + ((long)blk * S_TOK + t0 + mt * 128) * BDIM);
  const char* Bb = (const char*)(wcatT + ((long)blk * QKVW + nt * 128) * BDIM);
  stage_tile(ldsA, Ab, 256);
  stage_tile(ldsB, Bb, 256);
  __syncthreads();
  int wave = threadIdx.x >> 6, lane = threadIdx.x & 63;
  int wm = (wave >> 1) * 64, wn = (wave & 1) * 64;
  f32x4 acc[4][4] = {};
  mfma_slab(ldsA, ldsB, acc, wm, wn, lane);
  int rbase = (lane >> 4) * 4;
  int cb = lane & 15;
  long tokl0 = (long)mt * 128;
#pragma unroll
  for (int i = 0; i < 4; ++i) {
#pragma unroll
    for (int r = 0; r < 4; ++r) {
      long tokl = tokl0 + wm + i * 16 + rbase + r;
      bf16* dst = qkv + tokl * (NBLK * QKVW) + (long)blk * QKVW + nt * 128 + wn + cb;
#pragma unroll
      for (int j = 0; j < 4; ++j) dst[j * 16] = (bf16)acc[i][j][r];
    }
  }
}

// ---------------- K3: register-only block-axis attention ----------------
// 1 token per workgroup (4 waves); wave w handles heads {w, w+4, w+8}.
// lane (n = l>>3, c = l&7) owns chunk c (8 elems) of q/k/v row n.
__device__ __forceinline__ int4 shfl4(int4 v, int src) {
  int4 r;
  r.x = __shfl(v.x, src, 64); r.y = __shfl(v.y, src, 64);
  r.z = __shfl(v.z, src, 64); r.w = __shfl(v.w, src, 64);
  return r;
}

__global__ __launch_bounds__(256) void attn_kernel(
    const bf16* __restrict__ qkv, bf16* __restrict__ attn_out,
    float* __restrict__ out2, int t0) {
  __shared__ float smp[4][64];
  int t = threadIdx.x;
  int wave = t >> 6, lane = t & 63;
  int tl = blockIdx.x;
  long tok = t0 + tl;
  int n = lane >> 3, c = lane & 7;
  const bf16* base = qkv + (long)tl * (NBLK * QKVW) + n * QKVW + c * 8;
  float smacc[8] = {};
#pragma unroll
  for (int hi = 0; hi < 3; ++hi) {
    int h = wave + hi * 4;
    const bf16* hb = base + h * HD;
    int4 q4 = *(const int4*)(hb);
    int4 k4 = *(const int4*)(hb + E_DIM);
    int4 v4 = *(const int4*)(hb + 2 * E_DIM);
    bf16x8 q8 = __builtin_bit_cast(bf16x8, q4);
    float qf[8];
#pragma unroll
    for (int u = 0; u < 8; ++u) qf[u] = (float)q8[u];
    // partial scores over this lane's chunk c
    float sp[8];
#pragma unroll
    for (int m = 0; m < 8; ++m) {
      bf16x8 km = __builtin_bit_cast(bf16x8, shfl4(k4, m * 8 + c));
      float acc = 0.f;
#pragma unroll
      for (int u = 0; u < 8; ++u) acc += qf[u] * (float)km[u];
      sp[m] = acc;
    }
    // reduce over c (lanes n*8 .. n*8+7)
#pragma unroll
    for (int m = 0; m < 8; ++m) {
#pragma unroll
      for (int msk = 1; msk < 8; msk <<= 1) sp[m] += __shfl_xor(sp[m], msk, 64);
      sp[m] *= 0.125f;   // 1/sqrt(64)
    }
    // lane-local softmax over the 8 scores
    float mx = sp[0];
#pragma unroll
    for (int m = 1; m < 8; ++m) mx = fmaxf(mx, sp[m]);
    float a[8]; float ssum = 0.f;
#pragma unroll
    for (int m = 0; m < 8; ++m) { a[m] = __expf(sp[m] - mx); ssum += a[m]; }
    float inv = 1.f / ssum;
#pragma unroll
    for (int m = 0; m < 8; ++m) { a[m] *= inv; smacc[m] += a[m]; }
    // PV
    float of[8] = {};
#pragma unroll
    for (int m = 0; m < 8; ++m) {
      bf16x8 vm = __builtin_bit_cast(bf16x8, shfl4(v4, m * 8 + c));
#pragma unroll
      for (int u = 0; u < 8; ++u) of[u] += a[m] * (float)vm[u];
    }
    bf16x8 ov;
#pragma unroll
    for (int u = 0; u < 8; ++u) ov[u] = (bf16)of[u];
    *(int4*)(attn_out + ((long)n * S_TOK + tok) * E_DIM + h * HD + c * 8) =
        __builtin_bit_cast(int4, ov);
  }
  // score_mean: lane (n,c) contributes a[n][m=c]; select statically
  float sel = smacc[0];
#pragma unroll
  for (int m = 1; m < 8; ++m) if (c == m) sel = smacc[m];
  smp[wave][lane] = sel;
  __syncthreads();
  if (t < 64) {
    float v = (smp[0][t] + smp[1][t] + smp[2][t] + smp[3][t]) * (1.f / 12.f);
    out2[tok * 64 + t] = v;
  }
}

// ---------------- K4: final block GEMM (single dispatch, full 4096 tokens) ----------------
__global__ __launch_bounds__(256) void final_gemm(
    const bf16* __restrict__ attn_out, const bf16* __restrict__ wfinT,
    float* __restrict__ out) {
  __shared__ char ldsA[32768];
  __shared__ char ldsB[32768];
  int mt = blockIdx.y;    // 0..31
  int blk = blockIdx.z;
  int wave = threadIdx.x >> 6, lane = threadIdx.x & 63;
  int wm = (wave >> 1) * 64, wn = (wave & 1) * 64;
  f32x4 acc[4][4] = {};
  const char* Abase = (const char*)(attn_out + ((long)blk * S_TOK + mt * 128) * E_DIM);
  const char* Bbase = (const char*)(wfinT + (long)blk * BDIM * E_DIM);
  for (int kt = 0; kt < 6; ++kt) {
    stage_tile(ldsA, Abase + kt * 256, E_DIM * 2);
    stage_tile(ldsB, Bbase + kt * 256, E_DIM * 2);
    __syncthreads();
    mfma_slab(ldsA, ldsB, acc, wm, wn, lane);
    __syncthreads();
  }
  int rbase = (lane >> 4) * 4;
  int cb = lane & 15;
#pragma unroll
  for (int i = 0; i < 4; ++i) {
#pragma unroll
    for (int r = 0; r < 4; ++r) {
      long tok = (long)mt * 128 + wm + i * 16 + rbase + r;
      float* dst = out + tok * D_DIM + blk * BDIM + wn + cb;
#pragma unroll
      for (int j = 0; j < 4; ++j) dst[j * 16] = acc[i][j][r];
    }
  }
}

// ---------------- launcher ----------------
extern "C" void kernel_launch(void* const* d_in, const int* in_sizes, int n_in,
                              void* d_out, int out_size, void* d_ws, size_t ws_size,
                              hipStream_t stream) {
  const float* x     = (const float*)d_in[0];
  const float* wcomp = (const float*)d_in[1];
  const float* wq    = (const float*)d_in[2];
  const float* wk    = (const float*)d_in[3];
  const float* wv    = (const float*)d_in[4];
  const float* wfin  = (const float*)d_in[5];
  float* out  = (float*)d_out;
  float* out2 = out + (long)S_TOK * D_DIM;   // score_mean [4096][8][8]

  char* ws = (char*)d_ws;
  bf16* xg    = (bf16*)ws;                                  // 8,388,608 B
  bf16* wcatT = (bf16*)(ws + 8388608);                      // 4,718,592 B
  bf16* wfinT = (bf16*)(ws + 8388608 + 4718592);            // 1,572,864 B
  const long FIXED = 14680064;
  bf16* attnb = (bf16*)(ws + FIXED);                        // 50,331,648 B (8*4096*768*2)
  const long ATTNB = 50331648;
  char* dyn = ws + FIXED + ATTNB;
  long avail = (long)ws_size - (FIXED + ATTNB);
  long TC = avail > 0 ? avail / 36864 : 0;   // qkv chunk: 36864 B/token
  if (TC > 2048) TC = 2048;
  TC &= ~127L;
  if (TC < 128) TC = 128;
  bf16* qkvb = (bf16*)dyn;

  prep_weights<<<12288, 256, 0, stream>>>(wq, wk, wv, wfin, wcatT, wfinT);
  gate_kernel<<<S_TOK, 256, 0, stream>>>(x, wcomp, xg);
  for (int t0 = 0; t0 < S_TOK; t0 += (int)TC) {
    int tc = S_TOK - t0; if (tc > TC) tc = (int)TC;
    dim3 g2(18, tc / 128, 8);
    qkv_gemm<<<g2, 256, 0, stream>>>(xg, wcatT, qkvb, t0);
    attn_kernel<<<tc, 256, 0, stream>>>(qkvb, attnb, out2, t0);
  }
  dim3 g4(1, 32, 8);
  final_gemm<<<g4, 256, 0, stream>>>(attnb, wfinT, out);
}

// Round 16
// 210.733 us; speedup vs baseline: 1.0480x; 1.0480x over previous
//
#include <hip/hip_runtime.h>
#include <hip/hip_bf16.h>

typedef __bf16 bf16;
typedef __bf16 bf16x8 __attribute__((ext_vector_type(8)));
typedef float f32x4 __attribute__((ext_vector_type(4)));

#define S_TOK 4096   // S*B
#define D_DIM 1024
#define NBLK 8
#define BDIM 128
#define E_DIM 768
#define NH 12
#define HD 64
#define QKVW 2304    // 3*E

// ---------------- K0: weight prep (transpose + bf16 cast) ----------------
__global__ __launch_bounds__(256) void prep_weights(
    const float* __restrict__ wq, const float* __restrict__ wk,
    const float* __restrict__ wv, const float* __restrict__ wfin,
    bf16* __restrict__ wcatT, bf16* __restrict__ wfinT) {
  long idx = (long)blockIdx.x * 256 + threadIdx.x;
  const long NCAT = (long)NBLK * QKVW * BDIM;  // 2359296
  if (idx < NCAT) {
    int k = idx & (BDIM - 1);
    long rem = idx >> 7;           // n*QKVW + j
    int j = (int)(rem % QKVW);
    int n = (int)(rem / QKVW);
    const float* src; int jj;
    if (j < 768) { src = wq; jj = j; }
    else if (j < 1536) { src = wk; jj = j - 768; }
    else { src = wv; jj = j - 1536; }
    float v = src[((long)n * BDIM + k) * E_DIM + jj];
    wcatT[idx] = (bf16)v;
  } else {
    long i2 = idx - NCAT;          // over 8*128*768 = 786432
    if (i2 < (long)NBLK * BDIM * E_DIM) {
      int e = (int)(i2 % E_DIM);
      long rem = i2 / E_DIM;
      int d = (int)(rem & (BDIM - 1));
      int n = (int)(rem >> 7);
      float v = wfin[((long)n * E_DIM + e) * BDIM + d];
      wfinT[i2] = (bf16)v;
    }
  }
}

// ---------------- K1: competition gating ----------------
__global__ __launch_bounds__(256) void gate_kernel(
    const float* __restrict__ x, const float* __restrict__ wcomp,
    bf16* __restrict__ xg) {
  int tok = blockIdx.x;
  int t = threadIdx.x;
  int n = t >> 5;          // block 0..7 (32 lanes each)
  int l = t & 31;
  const float* xrow = x + (long)tok * D_DIM + n * BDIM;
  float xv[4]; float part = 0.f;
#pragma unroll
  for (int i = 0; i < 4; ++i) {
    int d = l + i * 32;
    xv[i] = xrow[d];
    part += xv[i] * wcomp[n * BDIM + d];
  }
#pragma unroll
  for (int m = 16; m >= 1; m >>= 1) part += __shfl_xor(part, m, 64);
  __shared__ float logits[NBLK];
  __shared__ float comp[NBLK];
  if (l == 0) logits[n] = part;
  __syncthreads();
  if (t == 0) {
    float mx = logits[0];
#pragma unroll
    for (int i = 1; i < 8; ++i) mx = fmaxf(mx, logits[i]);
    float s = 0.f, e[8];
#pragma unroll
    for (int i = 0; i < 8; ++i) { e[i] = __expf(logits[i] - mx); s += e[i]; }
    float inv = 1.f / s;
#pragma unroll
    for (int i = 0; i < 8; ++i) comp[i] = e[i] * inv;
  }
  __syncthreads();
  float c = comp[n];
  bf16* dst = xg + ((long)n * S_TOK + tok) * BDIM;
#pragma unroll
  for (int i = 0; i < 4; ++i) dst[l + i * 32] = (bf16)(xv[i] * c);
}

// ---------------- shared GEMM machinery (m97 structure) ----------------
__device__ __forceinline__ void stage_tile(char* lds, const char* g, long rstride) {
  int wave = threadIdx.x >> 6, lane = threadIdx.x & 63;
#pragma unroll
  for (int s = 0; s < 8; ++s) {
    int instr = wave * 8 + s;               // 0..31, 1KB each
    int row = instr * 4 + (lane >> 4);      // 0..127
    int chunk = (lane & 15) ^ (row & 7);    // pre-swizzled source chunk
    const char* src = g + (long)row * rstride + chunk * 16;
    __builtin_amdgcn_global_load_lds(
        (const __attribute__((address_space(1))) void*)src,
        (__attribute__((address_space(3))) void*)(lds + instr * 1024), 16, 0, 0);
  }
}

__device__ __forceinline__ bf16x8 ld_frag(const char* lds, int row, int kchunk) {
  int chunk = kchunk ^ (row & 7);
  return *(const bf16x8*)(lds + row * 256 + chunk * 16);
}

__device__ __forceinline__ void mfma_slab(const char* ldsA, const char* ldsB,
                                          f32x4 acc[4][4], int wm, int wn, int lane) {
#pragma unroll
  for (int ks = 0; ks < 4; ++ks) {
    int kchunk = ks * 4 + (lane >> 4);
    bf16x8 af[4], bfr[4];
#pragma unroll
    for (int i = 0; i < 4; ++i) af[i] = ld_frag(ldsA, wm + i * 16 + (lane & 15), kchunk);
#pragma unroll
    for (int j = 0; j < 4; ++j) bfr[j] = ld_frag(ldsB, wn + j * 16 + (lane & 15), kchunk);
#pragma unroll
    for (int i = 0; i < 4; ++i)
#pragma unroll
      for (int j = 0; j < 4; ++j)
        acc[i][j] = __builtin_amdgcn_mfma_f32_16x16x32_bf16(af[i], bfr[j], acc[i][j], 0, 0, 0);
  }
}

// ---------------- K2: QKV block GEMM (LDS epilogue for coalesced writes) ----------------
__global__ __launch_bounds__(256) void qkv_gemm(
    const bf16* __restrict__ xg, const bf16* __restrict__ wcatT,
    bf16* __restrict__ qkv, int t0) {
  __shared__ char ldsA[32768];
  __shared__ char ldsB[32768];
  int nt = blockIdx.x;    // 0..17
  int mt = blockIdx.y;
  int blk = blockIdx.z;
  const char* Ab = (const char*)(xg + ((long)blk * S_TOK + t0 + mt * 128) * BDIM);
  const char* Bb = (const char*)(wcatT + ((long)blk * QKVW + nt * 128) * BDIM);
  stage_tile(ldsA, Ab, 256);
  stage_tile(ldsB, Bb, 256);
  __syncthreads();
  int wave = threadIdx.x >> 6, lane = threadIdx.x & 63;
  int wm = (wave >> 1) * 64, wn = (wave & 1) * 64;
  f32x4 acc[4][4] = {};
  mfma_slab(ldsA, ldsB, acc, wm, wn, lane);
  // ---- epilogue: C tile through LDS, then coalesced 16B stores ----
  __syncthreads();   // all waves done reading A/B slabs
  bf16* cst = (bf16*)ldsA;   // [128 rows][128 cols] bf16, row stride 256B
  int rbase = (lane >> 4) * 4;
  int cb = lane & 15;
#pragma unroll
  for (int i = 0; i < 4; ++i)
#pragma unroll
    for (int j = 0; j < 4; ++j) {
      int col = wn + j * 16 + cb;
#pragma unroll
      for (int r = 0; r < 4; ++r)
        cst[(wm + i * 16 + rbase + r) * 128 + col] = (bf16)acc[i][j][r];
    }
  __syncthreads();
  int rr = threadIdx.x >> 4;         // 0..15 (row within pass)
  int co = (threadIdx.x & 15) * 8;   // element offset, 16 lanes cover 128 cols
  long tokl0 = (long)mt * 128;
#pragma unroll
  for (int p = 0; p < 8; ++p) {
    int row = rr + p * 16;
    bf16* dst = qkv + (tokl0 + row) * (NBLK * QKVW) + (long)blk * QKVW + nt * 128 + co;
    *(int4*)dst = *(const int4*)(cst + row * 128 + co);
  }
}

// ---------------- K3: register-only block-axis attention ----------------
__device__ __forceinline__ int4 shfl4(int4 v, int src) {
  int4 r;
  r.x = __shfl(v.x, src, 64); r.y = __shfl(v.y, src, 64);
  r.z = __shfl(v.z, src, 64); r.w = __shfl(v.w, src, 64);
  return r;
}

__global__ __launch_bounds__(256) void attn_kernel(
    const bf16* __restrict__ qkv, bf16* __restrict__ attn_out,
    float* __restrict__ out2, int t0) {
  __shared__ float smp[4][64];
  int t = threadIdx.x;
  int wave = t >> 6, lane = t & 63;
  int tl = blockIdx.x;
  long tok = t0 + tl;
  int n = lane >> 3, c = lane & 7;
  const bf16* base = qkv + (long)tl * (NBLK * QKVW) + n * QKVW + c * 8;
  float smacc[8] = {};
#pragma unroll
  for (int hi = 0; hi < 3; ++hi) {
    int h = wave + hi * 4;
    const bf16* hb = base + h * HD;
    int4 q4 = *(const int4*)(hb);
    int4 k4 = *(const int4*)(hb + E_DIM);
    int4 v4 = *(const int4*)(hb + 2 * E_DIM);
    bf16x8 q8 = __builtin_bit_cast(bf16x8, q4);
    float qf[8];
#pragma unroll
    for (int u = 0; u < 8; ++u) qf[u] = (float)q8[u];
    float sp[8];
#pragma unroll
    for (int m = 0; m < 8; ++m) {
      bf16x8 km = __builtin_bit_cast(bf16x8, shfl4(k4, m * 8 + c));
      float acc = 0.f;
#pragma unroll
      for (int u = 0; u < 8; ++u) acc += qf[u] * (float)km[u];
      sp[m] = acc;
    }
#pragma unroll
    for (int m = 0; m < 8; ++m) {
#pragma unroll
      for (int msk = 1; msk < 8; msk <<= 1) sp[m] += __shfl_xor(sp[m], msk, 64);
      sp[m] *= 0.125f;   // 1/sqrt(64)
    }
    float mx = sp[0];
#pragma unroll
    for (int m = 1; m < 8; ++m) mx = fmaxf(mx, sp[m]);
    float a[8]; float ssum = 0.f;
#pragma unroll
    for (int m = 0; m < 8; ++m) { a[m] = __expf(sp[m] - mx); ssum += a[m]; }
    float inv = 1.f / ssum;
#pragma unroll
    for (int m = 0; m < 8; ++m) { a[m] *= inv; smacc[m] += a[m]; }
    float of[8] = {};
#pragma unroll
    for (int m = 0; m < 8; ++m) {
      bf16x8 vm = __builtin_bit_cast(bf16x8, shfl4(v4, m * 8 + c));
#pragma unroll
      for (int u = 0; u < 8; ++u) of[u] += a[m] * (float)vm[u];
    }
    bf16x8 ov;
#pragma unroll
    for (int u = 0; u < 8; ++u) ov[u] = (bf16)of[u];
    *(int4*)(attn_out + ((long)n * S_TOK + tok) * E_DIM + h * HD + c * 8) =
        __builtin_bit_cast(int4, ov);
  }
  float sel = smacc[0];
#pragma unroll
  for (int m = 1; m < 8; ++m) if (c == m) sel = smacc[m];
  smp[wave][lane] = sel;
  __syncthreads();
  if (t < 64) {
    float v = (smp[0][t] + smp[1][t] + smp[2][t] + smp[3][t]) * (1.f / 12.f);
    out2[tok * 64 + t] = v;
  }
}

// ---------------- K4: final block GEMM — 2-phase double-buffered K pipeline ----------------
// grid 256 wg = 1 wg/CU (1 wave/SIMD): no co-resident waves to hide stage
// latency, so explicit dbuf pays here (unlike m99/m100's ~3 wg/CU regime).
// LDS 2*(32+32)KB = 128KB <= 160KB/CU.
__global__ __launch_bounds__(256) void final_gemm(
    const bf16* __restrict__ attn_out, const bf16* __restrict__ wfinT,
    float* __restrict__ out) {
  __shared__ char ldsA[2][32768];
  __shared__ char ldsB[2][32768];
  int mt = blockIdx.y;    // 0..31
  int blk = blockIdx.z;
  int wave = threadIdx.x >> 6, lane = threadIdx.x & 63;
  int wm = (wave >> 1) * 64, wn = (wave & 1) * 64;
  f32x4 acc[4][4] = {};
  const char* Abase = (const char*)(attn_out + ((long)blk * S_TOK + mt * 128) * E_DIM);
  const char* Bbase = (const char*)(wfinT + (long)blk * BDIM * E_DIM);
  // prologue: stage slab 0, wait
  stage_tile(ldsA[0], Abase, E_DIM * 2);
  stage_tile(ldsB[0], Bbase, E_DIM * 2);
  __syncthreads();
  int cur = 0;
  for (int kt = 0; kt < 5; ++kt) {
    // issue next slab's loads (async, into the other buffer)
    stage_tile(ldsA[cur ^ 1], Abase + (kt + 1) * 256, E_DIM * 2);
    stage_tile(ldsB[cur ^ 1], Bbase + (kt + 1) * 256, E_DIM * 2);
    // compute current slab while loads fly
    mfma_slab(ldsA[cur], ldsB[cur], acc, wm, wn, lane);
    __syncthreads();   // drains vmcnt (next slab ready) + all waves done reading cur
    cur ^= 1;
  }
  mfma_slab(ldsA[cur], ldsB[cur], acc, wm, wn, lane);  // epilogue slab 5
  int rbase = (lane >> 4) * 4;
  int cb = lane & 15;
#pragma unroll
  for (int i = 0; i < 4; ++i) {
#pragma unroll
    for (int r = 0; r < 4; ++r) {
      long tok = (long)mt * 128 + wm + i * 16 + rbase + r;
      float* dst = out + tok * D_DIM + blk * BDIM + wn + cb;
#pragma unroll
      for (int j = 0; j < 4; ++j) dst[j * 16] = acc[i][j][r];
    }
  }
}

// ---------------- launcher ----------------
extern "C" void kernel_launch(void* const* d_in, const int* in_sizes, int n_in,
                              void* d_out, int out_size, void* d_ws, size_t ws_size,
                              hipStream_t stream) {
  const float* x     = (const float*)d_in[0];
  const float* wcomp = (const float*)d_in[1];
  const float* wq    = (const float*)d_in[2];
  const float* wk    = (const float*)d_in[3];
  const float* wv    = (const float*)d_in[4];
  const float* wfin  = (const float*)d_in[5];
  float* out  = (float*)d_out;
  float* out2 = out + (long)S_TOK * D_DIM;   // score_mean [4096][8][8]

  char* ws = (char*)d_ws;
  bf16* xg    = (bf16*)ws;                                  // 8,388,608 B
  bf16* wcatT = (bf16*)(ws + 8388608);                      // 4,718,592 B
  bf16* wfinT = (bf16*)(ws + 8388608 + 4718592);            // 1,572,864 B
  const long FIXED = 14680064;
  bf16* attnb = (bf16*)(ws + FIXED);                        // 50,331,648 B (8*4096*768*2)
  const long ATTNB = 50331648;
  char* dyn = ws + FIXED + ATTNB;
  long avail = (long)ws_size - (FIXED + ATTNB);
  long TC = avail > 0 ? avail / 36864 : 0;   // qkv chunk: 36864 B/token
  if (TC > S_TOK) TC = S_TOK;                // ws=256MiB -> TC=4096, single chunk
  TC &= ~127L;
  if (TC < 128) TC = 128;
  bf16* qkvb = (bf16*)dyn;

  prep_weights<<<12288, 256, 0, stream>>>(wq, wk, wv, wfin, wcatT, wfinT);
  gate_kernel<<<S_TOK, 256, 0, stream>>>(x, wcomp, xg);
  for (int t0 = 0; t0 < S_TOK; t0 += (int)TC) {
    int tc = S_TOK - t0; if (tc > TC) tc = (int)TC;
    dim3 g2(18, tc / 128, 8);
    qkv_gemm<<<g2, 256, 0, stream>>>(xg, wcatT, qkvb, t0);
    attn_kernel<<<tc, 256, 0, stream>>>(qkvb, attnb, out2, t0);
  }
  dim3 g4(1, 32, 8);
  final_gemm<<<g4, 256, 0, stream>>>(attnb, wfinT, out);
}